// Round 4
// baseline (67.570 us; speedup 1.0000x reference)
//
#include <hip/hip_runtime.h>

typedef float floatx4 __attribute__((ext_vector_type(4)));

constexpr int BLOCK = 256;
constexpr int PPT   = 8;    // points per thread (2 KB contiguous per wave per row-visit)
constexpr int MPB   = 32;   // models per block (point fetch amortized 32x)

__global__ __launch_bounds__(BLOCK) void essential_msac_kernel(
    const float*  __restrict__ models,  // B x 3 x 4
    const float4* __restrict__ pts,     // N x (x1,y1,x2,y2)
    const float*  __restrict__ K1,      // 3x3
    const float*  __restrict__ K2,      // 3x3
    float*        __restrict__ out,     // B x N
    int B, int N)
{
    __shared__ float Es[MPB][9];

    const int bm0  = blockIdx.y * MPB;
    const int mEnd = min(MPB, B - bm0);

    if ((int)threadIdx.x < mEnd) {
        const float* m = models + (size_t)(bm0 + threadIdx.x) * 12;
        const float t0 = m[3], t1 = m[7], t2 = m[11];
        #pragma unroll
        for (int j = 0; j < 3; ++j) {
            const float R0 = m[0 + j], R1 = m[4 + j], R2 = m[8 + j];
            Es[threadIdx.x][0 + j] = fmaf(-t2, R1,  t1 * R2);
            Es[threadIdx.x][3 + j] = fmaf( t2, R0, -t0 * R2);
            Es[threadIdx.x][6 + j] = fmaf(-t1, R0,  t0 * R1);
        }
    }
    __syncthreads();

    const float f1 = (K1[0] + K1[4]) * 0.5f;
    const float f2 = (K2[0] + K2[4]) * 0.5f;
    const float thr = (1.0f / f1 + 1.0f / f2) * 0.5f;
    const float inv_thr2 = 1.0f / (thr * thr);

    const int n0 = (blockIdx.x * BLOCK + threadIdx.x) * PPT;
    if (n0 >= N) return;
    const bool full = (n0 + PPT <= N);   // N % 8 == 0 -> always true for in-range threads

    // Load this thread's 8 points ONCE; reuse across all MPB models.
    float4 p[PPT];
    #pragma unroll
    for (int k = 0; k < PPT; ++k)
        p[k] = (full || n0 + k < N) ? pts[n0 + k] : make_float4(0.f, 0.f, 0.f, 1.f);

    float* o = out + (size_t)bm0 * N + n0;
    for (int mi = 0; mi < mEnd; ++mi) {
        float E[9];
        #pragma unroll
        for (int j = 0; j < 9; ++j) E[j] = Es[mi][j];   // LDS broadcast, uniform addr

        float r[PPT];
        #pragma unroll
        for (int k = 0; k < PPT; ++k) {
            const float x = p[k].x, y = p[k].y;   // hom1 = (x, y, 1)
            const float u = p[k].z, v = p[k].w;   // hom2 = (u, v, 1)

            const float a0 = fmaf(E[0], x, fmaf(E[1], y, E[2]));
            const float a1 = fmaf(E[3], x, fmaf(E[4], y, E[5]));
            const float b0 = fmaf(E[0], u, fmaf(E[3], v, E[6]));
            const float b1 = fmaf(E[1], u, fmaf(E[4], v, E[7]));
            const float b2 = fmaf(E[2], u, fmaf(E[5], v, E[8]));

            const float jj = fmaf(a0, a0, fmaf(a1, a1, fmaf(b0, b0, b1 * b1)));
            const float s  = fmaf(x, b0, fmaf(y, b1, b2));
            const float d  = __fdividef(s * s, jj) * inv_thr2;
            r[k] = 1.0f - fminf(fmaxf(d, 0.0f), 1.0f);
        }

        if (full) {
            floatx4 v0 = { r[0], r[1], r[2], r[3] };
            floatx4 v1 = { r[4], r[5], r[6], r[7] };
            __builtin_nontemporal_store(v0, reinterpret_cast<floatx4*>(o));
            __builtin_nontemporal_store(v1, reinterpret_cast<floatx4*>(o) + 1);
        } else {
            for (int k = 0; k < PPT && n0 + k < N; ++k)
                __builtin_nontemporal_store(r[k], o + k);
        }
        o += N;   // next model's row
    }
}

extern "C" void kernel_launch(void* const* d_in, const int* in_sizes, int n_in,
                              void* d_out, int out_size, void* d_ws, size_t ws_size,
                              hipStream_t stream)
{
    const float* models = (const float*)d_in[0];
    const float* points = (const float*)d_in[1];
    const float* K1     = (const float*)d_in[2];
    const float* K2     = (const float*)d_in[3];
    float* out = (float*)d_out;

    const int B = in_sizes[0] / 12;   // (B,3,4)
    const int N = in_sizes[1] / 4;    // (N,4)

    dim3 grid((N + BLOCK * PPT - 1) / (BLOCK * PPT), (B + MPB - 1) / MPB);
    essential_msac_kernel<<<grid, BLOCK, 0, stream>>>(
        models, (const float4*)points, K1, K2, out, B, N);
}

// Round 6
// 51.633 us; speedup vs baseline: 1.3086x; 1.3086x over previous
//
#include <hip/hip_runtime.h>

constexpr int BLOCK = 256;
constexpr int PPT   = 4;    // 16B/lane coalesced stores
constexpr int MPB   = 32;   // point fetch amortized 32x

__global__ __launch_bounds__(BLOCK) void essential_msac_kernel(
    const float*  __restrict__ models,  // B x 3 x 4
    const float4* __restrict__ pts,     // N x (x1,y1,x2,y2)
    const float*  __restrict__ K1,      // 3x3
    const float*  __restrict__ K2,      // 3x3
    float*        __restrict__ out,     // B x N
    int B, int N)
{
    __shared__ float Es[MPB][9];

    const int bm0  = blockIdx.y * MPB;
    const int mEnd = min(MPB, B - bm0);

    if ((int)threadIdx.x < mEnd) {
        const float* m = models + (size_t)(bm0 + threadIdx.x) * 12;
        const float t0 = m[3], t1 = m[7], t2 = m[11];
        #pragma unroll
        for (int j = 0; j < 3; ++j) {
            const float R0 = m[0 + j], R1 = m[4 + j], R2 = m[8 + j];
            Es[threadIdx.x][0 + j] = fmaf(-t2, R1,  t1 * R2);
            Es[threadIdx.x][3 + j] = fmaf( t2, R0, -t0 * R2);
            Es[threadIdx.x][6 + j] = fmaf(-t1, R0,  t0 * R1);
        }
    }
    __syncthreads();

    const float f1 = (K1[0] + K1[4]) * 0.5f;
    const float f2 = (K2[0] + K2[4]) * 0.5f;
    const float thr = (1.0f / f1 + 1.0f / f2) * 0.5f;
    const float inv_thr2 = 1.0f / (thr * thr);

    const int n0 = (blockIdx.x * BLOCK + threadIdx.x) * PPT;
    if (n0 >= N) return;   // N % 4 == 0: survivors take the full float4 path

    // Load this thread's 4 points ONCE; reuse across all MPB models.
    float4 p[PPT];
    #pragma unroll
    for (int k = 0; k < PPT; ++k) p[k] = pts[n0 + k];

    float* o = out + (size_t)bm0 * N + n0;
    for (int mi = 0; mi < mEnd; ++mi) {
        float E[9];
        #pragma unroll
        for (int j = 0; j < 9; ++j) E[j] = Es[mi][j];   // LDS broadcast

        float r[PPT];
        #pragma unroll
        for (int k = 0; k < PPT; ++k) {
            const float x = p[k].x, y = p[k].y;   // hom1 = (x, y, 1)
            const float u = p[k].z, v = p[k].w;   // hom2 = (u, v, 1)

            const float a0 = fmaf(E[0], x, fmaf(E[1], y, E[2]));
            const float a1 = fmaf(E[3], x, fmaf(E[4], y, E[5]));
            const float b0 = fmaf(E[0], u, fmaf(E[3], v, E[6]));
            const float b1 = fmaf(E[1], u, fmaf(E[4], v, E[7]));
            const float b2 = fmaf(E[2], u, fmaf(E[5], v, E[8]));

            const float jj = fmaf(a0, a0, fmaf(a1, a1, fmaf(b0, b0, b1 * b1)));
            const float s  = fmaf(x, b0, fmaf(y, b1, b2));
            const float d  = __fdividef(s * s, jj) * inv_thr2;
            r[k] = 1.0f - fminf(fmaxf(d, 0.0f), 1.0f);
        }

        // Regular (cached) store: let Infinity Cache absorb the write stream.
        *reinterpret_cast<float4*>(o) = make_float4(r[0], r[1], r[2], r[3]);
        o += N;
    }
}

extern "C" void kernel_launch(void* const* d_in, const int* in_sizes, int n_in,
                              void* d_out, int out_size, void* d_ws, size_t ws_size,
                              hipStream_t stream)
{
    const float* models = (const float*)d_in[0];
    const float* points = (const float*)d_in[1];
    const float* K1     = (const float*)d_in[2];
    const float* K2     = (const float*)d_in[3];
    float* out = (float*)d_out;

    const int B = in_sizes[0] / 12;   // (B,3,4)
    const int N = in_sizes[1] / 4;    // (N,4)

    dim3 grid((N + BLOCK * PPT - 1) / (BLOCK * PPT), (B + MPB - 1) / MPB);
    essential_msac_kernel<<<grid, BLOCK, 0, stream>>>(
        models, (const float4*)points, K1, K2, out, B, N);
}

// Round 7
// 40.117 us; speedup vs baseline: 1.6843x; 1.2871x over previous
//
#include <hip/hip_runtime.h>

typedef float floatx2 __attribute__((ext_vector_type(2)));
typedef float floatx4 __attribute__((ext_vector_type(4)));

constexpr int BLOCK = 256;
constexpr int PPT   = 4;    // 16B/lane coalesced stores
constexpr int MPB   = 32;   // point fetch amortized 32x

static __device__ __forceinline__ floatx2 fma2(floatx2 a, floatx2 b, floatx2 c) {
    return __builtin_elementwise_fma(a, b, c);   // -> llvm.fma.v2f32 -> v_pk_fma_f32 (gfx90a+)
}

__global__ __launch_bounds__(BLOCK) void essential_msac_kernel(
    const float*  __restrict__ models,  // B x 3 x 4
    const float4* __restrict__ pts,     // N x (x1,y1,x2,y2)
    const float*  __restrict__ K1,      // 3x3
    const float*  __restrict__ K2,      // 3x3
    float*        __restrict__ out,     // B x N
    int B, int N)
{
    __shared__ float Es[MPB][9];

    const int bm0  = blockIdx.y * MPB;
    const int mEnd = min(MPB, B - bm0);

    if ((int)threadIdx.x < mEnd) {
        const float* m = models + (size_t)(bm0 + threadIdx.x) * 12;
        const float t0 = m[3], t1 = m[7], t2 = m[11];
        #pragma unroll
        for (int j = 0; j < 3; ++j) {
            const float R0 = m[0 + j], R1 = m[4 + j], R2 = m[8 + j];
            Es[threadIdx.x][0 + j] = fmaf(-t2, R1,  t1 * R2);
            Es[threadIdx.x][3 + j] = fmaf( t2, R0, -t0 * R2);
            Es[threadIdx.x][6 + j] = fmaf(-t1, R0,  t0 * R1);
        }
    }
    __syncthreads();

    const float f1 = (K1[0] + K1[4]) * 0.5f;
    const float f2 = (K2[0] + K2[4]) * 0.5f;
    const float thr  = (1.0f / f1 + 1.0f / f2) * 0.5f;
    const float thr2 = thr * thr;
    const floatx2 thr2v = { thr2,  thr2 };
    const floatx2 onev  = { 1.0f,  1.0f };
    const floatx2 nonev = { -1.0f, -1.0f };
    const floatx2 zerov = { 0.0f,  0.0f };

    const int n0 = (blockIdx.x * BLOCK + threadIdx.x) * PPT;
    if (n0 >= N) return;   // N % 4 == 0: survivors take the full float4 path

    // Load 4 points once; pack as point-pairs for dual-FP32 math.
    float4 p[PPT];
    #pragma unroll
    for (int k = 0; k < PPT; ++k) p[k] = pts[n0 + k];

    floatx2 px[2], py[2], pu[2], pv[2];
    #pragma unroll
    for (int g = 0; g < 2; ++g) {
        px[g] = { p[2*g].x, p[2*g+1].x };
        py[g] = { p[2*g].y, p[2*g+1].y };
        pu[g] = { p[2*g].z, p[2*g+1].z };
        pv[g] = { p[2*g].w, p[2*g+1].w };
    }

    float* o = out + (size_t)bm0 * N + n0;
    for (int mi = 0; mi < mEnd; ++mi) {
        const float* e = Es[mi];   // LDS broadcast (uniform addr)
        const floatx2 E0 = {e[0],e[0]}, E1 = {e[1],e[1]}, E2 = {e[2],e[2]};
        const floatx2 E3 = {e[3],e[3]}, E4 = {e[4],e[4]}, E5 = {e[5],e[5]};
        const floatx2 E6 = {e[6],e[6]}, E7 = {e[7],e[7]}, E8 = {e[8],e[8]};

        floatx2 rr[2];
        #pragma unroll
        for (int g = 0; g < 2; ++g) {
            const floatx2 a0 = fma2(E0, px[g], fma2(E1, py[g], E2));
            const floatx2 a1 = fma2(E3, px[g], fma2(E4, py[g], E5));
            const floatx2 b0 = fma2(E0, pu[g], fma2(E3, pv[g], E6));
            const floatx2 b1 = fma2(E1, pu[g], fma2(E4, pv[g], E7));
            const floatx2 b2 = fma2(E2, pu[g], fma2(E5, pv[g], E8));

            const floatx2 jj  = fma2(a0, a0, fma2(a1, a1, fma2(b0, b0, b1 * b1)));
            const floatx2 s   = fma2(px[g], b0, fma2(py[g], b1, b2));
            const floatx2 num = s * s;
            const floatx2 jjt = jj * thr2v;
            const floatx2 rj  = { __builtin_amdgcn_rcpf(jjt.x),
                                  __builtin_amdgcn_rcpf(jjt.y) };
            const floatx2 d   = num * rj;                 // d >= 0 by construction
            const floatx2 r   = fma2(d, nonev, onev);     // 1 - d
            rr[g] = __builtin_elementwise_max(r, zerov);  // == 1 - clip(d,0,1)
        }

        floatx4 v4 = { rr[0].x, rr[0].y, rr[1].x, rr[1].y };
        *reinterpret_cast<floatx4*>(o) = v4;   // regular cached store
        o += N;
    }
}

extern "C" void kernel_launch(void* const* d_in, const int* in_sizes, int n_in,
                              void* d_out, int out_size, void* d_ws, size_t ws_size,
                              hipStream_t stream)
{
    const float* models = (const float*)d_in[0];
    const float* points = (const float*)d_in[1];
    const float* K1     = (const float*)d_in[2];
    const float* K2     = (const float*)d_in[3];
    float* out = (float*)d_out;

    const int B = in_sizes[0] / 12;   // (B,3,4)
    const int N = in_sizes[1] / 4;    // (N,4)

    dim3 grid((N + BLOCK * PPT - 1) / (BLOCK * PPT), (B + MPB - 1) / MPB);
    essential_msac_kernel<<<grid, BLOCK, 0, stream>>>(
        models, (const float4*)points, K1, K2, out, B, N);
}

// Round 8
// 40.059 us; speedup vs baseline: 1.6867x; 1.0014x over previous
//
#include <hip/hip_runtime.h>

typedef float floatx2 __attribute__((ext_vector_type(2)));
typedef float floatx4 __attribute__((ext_vector_type(4)));

constexpr int BLOCK = 256;
constexpr int PPT   = 4;    // 16B/lane coalesced stores
constexpr int MPB   = 32;   // point fetch amortized 32x

static __device__ __forceinline__ floatx2 fma2(floatx2 a, floatx2 b, floatx2 c) {
    return __builtin_elementwise_fma(a, b, c);   // -> v_pk_fma_f32 (verified: engaged round 7)
}

__global__ __launch_bounds__(BLOCK) void essential_msac_kernel(
    const float*  __restrict__ models,  // B x 3 x 4
    const float4* __restrict__ pts,     // N x (x1,y1,x2,y2)
    const float*  __restrict__ K1,      // 3x3
    const float*  __restrict__ K2,      // 3x3
    float*        __restrict__ out,     // B x N
    int B, int N)
{
    __shared__ float Es[MPB][9];

    const int bm0  = blockIdx.y * MPB;
    const int mEnd = min(MPB, B - bm0);

    if ((int)threadIdx.x < mEnd) {
        const float* m = models + (size_t)(bm0 + threadIdx.x) * 12;
        const float t0 = m[3], t1 = m[7], t2 = m[11];
        #pragma unroll
        for (int j = 0; j < 3; ++j) {
            const float R0 = m[0 + j], R1 = m[4 + j], R2 = m[8 + j];
            Es[threadIdx.x][0 + j] = fmaf(-t2, R1,  t1 * R2);
            Es[threadIdx.x][3 + j] = fmaf( t2, R0, -t0 * R2);
            Es[threadIdx.x][6 + j] = fmaf(-t1, R0,  t0 * R1);
        }
    }
    __syncthreads();

    const float f1 = (K1[0] + K1[4]) * 0.5f;
    const float f2 = (K2[0] + K2[4]) * 0.5f;
    const float thr  = (1.0f / f1 + 1.0f / f2) * 0.5f;
    const float thr2 = thr * thr;
    const floatx2 thr2v = { thr2,  thr2 };
    const floatx2 onev  = { 1.0f,  1.0f };
    const floatx2 nonev = { -1.0f, -1.0f };
    const floatx2 zerov = { 0.0f,  0.0f };

    const int n0 = (blockIdx.x * BLOCK + threadIdx.x) * PPT;
    if (n0 >= N) return;   // N % 4 == 0

    float4 p[PPT];
    #pragma unroll
    for (int k = 0; k < PPT; ++k) p[k] = pts[n0 + k];

    floatx2 px[2], py[2], pu[2], pv[2];
    #pragma unroll
    for (int g = 0; g < 2; ++g) {
        px[g] = { p[2*g].x, p[2*g+1].x };
        py[g] = { p[2*g].y, p[2*g+1].y };
        pu[g] = { p[2*g].z, p[2*g+1].z };
        pv[g] = { p[2*g].w, p[2*g+1].w };
    }

    // Per-model result (4 outputs) from LDS-resident E.
    auto comp = [&](const float* e) -> floatx4 {
        const floatx2 E0 = {e[0],e[0]}, E1 = {e[1],e[1]}, E2 = {e[2],e[2]};
        const floatx2 E3 = {e[3],e[3]}, E4 = {e[4],e[4]}, E5 = {e[5],e[5]};
        const floatx2 E6 = {e[6],e[6]}, E7 = {e[7],e[7]}, E8 = {e[8],e[8]};
        floatx2 rr[2];
        #pragma unroll
        for (int g = 0; g < 2; ++g) {
            const floatx2 a0 = fma2(E0, px[g], fma2(E1, py[g], E2));
            const floatx2 a1 = fma2(E3, px[g], fma2(E4, py[g], E5));
            const floatx2 b0 = fma2(E0, pu[g], fma2(E3, pv[g], E6));
            const floatx2 b1 = fma2(E1, pu[g], fma2(E4, pv[g], E7));
            const floatx2 b2 = fma2(E2, pu[g], fma2(E5, pv[g], E8));

            const floatx2 jj  = fma2(a0, a0, fma2(a1, a1, fma2(b0, b0, b1 * b1)));
            const floatx2 s   = fma2(px[g], b0, fma2(py[g], b1, b2));
            const floatx2 num = s * s;
            const floatx2 jjt = jj * thr2v;
            const floatx2 rj  = { __builtin_amdgcn_rcpf(jjt.x),
                                  __builtin_amdgcn_rcpf(jjt.y) };
            const floatx2 d   = num * rj;
            const floatx2 r   = fma2(d, nonev, onev);     // 1 - d
            rr[g] = __builtin_elementwise_max(r, zerov);
        }
        return floatx4{ rr[0].x, rr[0].y, rr[1].x, rr[1].y };
    };

    float* o = out + (size_t)bm0 * N + n0;
    int mi = 0;
    // 2-model unroll: two independent result vectors -> >=2 outstanding stores
    for (; mi + 2 <= mEnd; mi += 2) {
        const floatx4 va = comp(Es[mi]);
        const floatx4 vb = comp(Es[mi + 1]);
        *reinterpret_cast<floatx4*>(o)     = va;
        *reinterpret_cast<floatx4*>(o + N) = vb;
        o += 2 * (size_t)N;
    }
    if (mi < mEnd) {
        const floatx4 va = comp(Es[mi]);
        *reinterpret_cast<floatx4*>(o) = va;
    }
}

extern "C" void kernel_launch(void* const* d_in, const int* in_sizes, int n_in,
                              void* d_out, int out_size, void* d_ws, size_t ws_size,
                              hipStream_t stream)
{
    const float* models = (const float*)d_in[0];
    const float* points = (const float*)d_in[1];
    const float* K1     = (const float*)d_in[2];
    const float* K2     = (const float*)d_in[3];
    float* out = (float*)d_out;

    const int B = in_sizes[0] / 12;   // (B,3,4)
    const int N = in_sizes[1] / 4;    // (N,4)

    dim3 grid((N + BLOCK * PPT - 1) / (BLOCK * PPT), (B + MPB - 1) / MPB);
    essential_msac_kernel<<<grid, BLOCK, 0, stream>>>(
        models, (const float4*)points, K1, K2, out, B, N);
}